// Round 12
// baseline (141.732 us; speedup 1.0000x reference)
//
#include <hip/hip_runtime.h>
#include <hip/hip_bf16.h>

#define NB 4
#define NN 4096

typedef short  bf16x8 __attribute__((ext_vector_type(8)));
typedef float  f32x4  __attribute__((ext_vector_type(4)));

static __device__ __forceinline__ ushort f2bf(float f) {
    unsigned u = __float_as_uint(f);
    u += 0x7fffu + ((u >> 16) & 1u);
    return (ushort)(u >> 16);
}
static __device__ __forceinline__ float bflo(unsigned w) { return __uint_as_float(w << 16); }
static __device__ __forceinline__ float bfhi(unsigned w) { return __uint_as_float(w & 0xffff0000u); }

// ---------------- prep: x -> xt (channel-last bf16), conv weights reordered bf16 ----------------
__global__ __launch_bounds__(256) void prep(
    const float* __restrict__ x, const float* __restrict__ w1, const float* __restrict__ w2,
    ushort* __restrict__ xt, ushort* __restrict__ W1r, ushort* __restrict__ W2r)
{
    const int tid = threadIdx.x;
    const int blk = blockIdx.x;
    if (blk < 256) {
        __shared__ float Ts[64][66];
        const int b = blk >> 6, n0 = (blk & 63) * 64;
        const int wv = tid >> 6, lane = tid & 63;
        #pragma unroll
        for (int i = 0; i < 16; ++i) {
            int ci = i * 4 + wv, nn = lane;
            Ts[ci][nn] = x[((size_t)b * 64 + ci) * NN + n0 + nn];
        }
        __syncthreads();
        #pragma unroll
        for (int i = 0; i < 16; ++i) {
            int nn = i * 4 + wv, ci = lane;
            xt[((size_t)b * NN + n0 + nn) * 64 + ci] = f2bf(Ts[ci][nn]);
        }
    } else if (blk < 258) {
        const int base = (blk - 256) * 9216;
        #pragma unroll
        for (int i = 0; i < 36; ++i) {
            int e = base + i * 256 + tid;
            int co = e / 576, k = e % 576, tap = k >> 6, ci = k & 63;
            W1r[e] = f2bf(w1[((size_t)co * 64 + ci) * 9 + tap]);
        }
    } else {
        const int base = (blk - 258) * 9216;
        #pragma unroll
        for (int i = 0; i < 36; ++i) {
            int e = base + i * 256 + tid;
            int co = e / 288, k = e % 288, tap = k >> 5, ci = k & 31;
            W2r[e] = f2bf(w2[((size_t)co * 32 + ci) * 9 + tap]);
        }
    }
}

// ---------------- conv1: 64ci -> 32co, MFMA implicit GEMM ----------------
__global__ __launch_bounds__(256) void conv1_mfma(
    const ushort* __restrict__ xt, const ushort* __restrict__ W1r,
    const float* __restrict__ bng, const float* __restrict__ bnb,
    const float* __restrict__ bnm, const float* __restrict__ bnv,
    ushort* __restrict__ y1t)
{
    __shared__ __align__(16) ushort As[32 * 600];
    __shared__ __align__(16) ushort Xs[24 * 66 * 8];

    const int tid = threadIdx.x;
    const int h = blockIdx.x, b = blockIdx.y;

    #pragma unroll
    for (int i = 0; i < 9; ++i) {
        int cid = i * 256 + tid;
        int row = cid / 72, off = cid % 72;
        *(uint4*)&As[row * 600 + off * 8] = *(const uint4*)(W1r + (size_t)cid * 8);
    }
    #pragma unroll
    for (int r = 0; r < 3; ++r) {
        int gh = h - 1 + r;
        #pragma unroll
        for (int i = 0; i < 2; ++i) {
            int cid = i * 256 + tid;
            int w_ = cid >> 3, cc = cid & 7;
            uint4 v = {0, 0, 0, 0};
            if ((unsigned)gh < 64u)
                v = *(const uint4*)(xt + ((size_t)(b * NN + gh * 64) * 64) + (size_t)cid * 8);
            *(uint4*)&Xs[((r * 8 + cc) * 66 + (w_ + 1)) * 8] = v;
        }
    }
    if (tid < 48) {
        int r = tid >> 4, q = tid & 15, cc = q >> 1, side = (q & 1) * 65;
        uint4 z = {0, 0, 0, 0};
        *(uint4*)&Xs[((r * 8 + cc) * 66 + side) * 8] = z;
    }
    __syncthreads();

    const int lane = tid & 63, wv = tid >> 6;
    const int quad = lane >> 4, l15 = lane & 15;
    const int ch = wv & 1, ph = wv >> 1;

    f32x4 acc[2] = {{0.f,0.f,0.f,0.f},{0.f,0.f,0.f,0.f}};
    #pragma unroll
    for (int kk = 0; kk < 18; ++kk) {
        const int tap = kk >> 1;
        const int dyr = tap / 3, dx = tap % 3;
        bf16x8 af = *(const bf16x8*)&As[(ch * 16 + l15) * 600 + kk * 32 + quad * 8];
        #pragma unroll
        for (int s = 0; s < 2; ++s) {
            int p = ph * 32 + s * 16 + l15;
            bf16x8 bf = *(const bf16x8*)&Xs[((dyr * 8 + (kk & 1) * 4 + quad) * 66 + p + dx) * 8];
            acc[s] = __builtin_amdgcn_mfma_f32_16x16x32_bf16(af, bf, acc[s], 0, 0, 0);
        }
    }

    const int cb = ch * 16 + quad * 4;
    float sc[4], bs[4];
    #pragma unroll
    for (int r = 0; r < 4; ++r) {
        int co = cb + r;
        sc[r] = bng[co] / sqrtf(bnv[co] + 1e-5f);
        bs[r] = bnb[co] - bnm[co] * sc[r];
    }
    #pragma unroll
    for (int s = 0; s < 2; ++s) {
        int p = ph * 32 + s * 16 + l15;
        ushort u4[4];
        #pragma unroll
        for (int r = 0; r < 4; ++r) {
            float pre = acc[s][r] * sc[r] + bs[r];
            u4[r] = f2bf(pre / (1.f + __expf(-pre)));
        }
        *(uint2*)&y1t[((size_t)(b * NN + h * 64 + p)) * 32 + cb] = *(uint2*)u4;
    }
}

// ---------------- conv2 + fused qkv ----------------
// vt in BLOCKED layout: vt[b][tile(128)][c(64)][slot(32)], slot = quad*8 + half*4 + r
// holding pixel m = tile*32 + half*16 + quad*4 + r. y stored bf16 [b][c][n].
__global__ __launch_bounds__(256) void conv2qkv(
    const ushort* __restrict__ y1t, const ushort* __restrict__ W2r,
    const float* __restrict__ bng, const float* __restrict__ bnb,
    const float* __restrict__ bnm, const float* __restrict__ bnv,
    const float* __restrict__ qw, const float* __restrict__ qb,
    const float* __restrict__ kw, const float* __restrict__ kb,
    const float* __restrict__ vw, const float* __restrict__ vb,
    ushort* __restrict__ yb, ushort* __restrict__ q8,
    ushort* __restrict__ ko, ushort* __restrict__ vt)
{
    __shared__ __align__(16) ushort As[64 * 312];
    __shared__ __align__(16) ushort Xs[12 * 66 * 8];
    __shared__ __align__(16) ushort Yt[64 * 76];
    __shared__ __align__(16) ushort Wq[80 * 76];
    __shared__ float Bv[80];

    const int tid = threadIdx.x;
    const int h = blockIdx.x, b = blockIdx.y;

    #pragma unroll
    for (int i = 0; i < 9; ++i) {
        int cid = i * 256 + tid;
        int row = cid / 36, off = cid % 36;
        *(uint4*)&As[row * 312 + off * 8] = *(const uint4*)(W2r + (size_t)cid * 8);
    }
    #pragma unroll
    for (int r = 0; r < 3; ++r) {
        int gh = h - 1 + r;
        int cid = tid;
        int w_ = cid >> 2, cc = cid & 3;
        uint4 v = {0, 0, 0, 0};
        if ((unsigned)gh < 64u)
            v = *(const uint4*)(y1t + ((size_t)(b * NN + gh * 64) * 32) + (size_t)cid * 8);
        *(uint4*)&Xs[((r * 4 + cc) * 66 + (w_ + 1)) * 8] = v;
    }
    if (tid < 24) {
        int r = tid >> 3, q = tid & 7, cc = q >> 1, side = (q & 1) * 65;
        uint4 z = {0, 0, 0, 0};
        *(uint4*)&Xs[((r * 4 + cc) * 66 + side) * 8] = z;
    }
    for (int i = tid; i < 2560; i += 256) {
        int chw = i >> 5, c2 = (i & 31) * 2;
        const float* src = (chw < 8) ? (qw + chw * 64 + c2)
                         : (chw < 16) ? (kw + (chw - 8) * 64 + c2)
                         : (vw + (chw - 16) * 64 + c2);
        float2 v2 = *(const float2*)src;
        *(unsigned*)&Wq[chw * 76 + c2] = ((unsigned)f2bf(v2.y) << 16) | f2bf(v2.x);
    }
    if (tid < 80) Bv[tid] = (tid < 8) ? qb[tid] : (tid < 16) ? kb[tid - 8] : vb[tid - 16];
    __syncthreads();

    const int lane = tid & 63, wv = tid >> 6;
    const int quad = lane >> 4, l15 = lane & 15;

    f32x4 acc[4] = {{0.f,0.f,0.f,0.f},{0.f,0.f,0.f,0.f},{0.f,0.f,0.f,0.f},{0.f,0.f,0.f,0.f}};
    #pragma unroll
    for (int kk = 0; kk < 9; ++kk) {
        const int dyr = kk / 3, dx = kk % 3;
        bf16x8 af = *(const bf16x8*)&As[(wv * 16 + l15) * 312 + kk * 32 + quad * 8];
        #pragma unroll
        for (int s = 0; s < 4; ++s) {
            int p = s * 16 + l15;
            bf16x8 bf = *(const bf16x8*)&Xs[((dyr * 4 + quad) * 66 + p + dx) * 8];
            acc[s] = __builtin_amdgcn_mfma_f32_16x16x32_bf16(af, bf, acc[s], 0, 0, 0);
        }
    }

    const int cb = wv * 16 + quad * 4;
    float sc[4], bs[4];
    #pragma unroll
    for (int r = 0; r < 4; ++r) {
        int co = cb + r;
        sc[r] = bng[co] / sqrtf(bnv[co] + 1e-5f);
        bs[r] = bnb[co] - bnm[co] * sc[r];
    }
    #pragma unroll
    for (int s = 0; s < 4; ++s) {
        int p = s * 16 + l15;
        #pragma unroll
        for (int r = 0; r < 4; ++r) {
            float pre = acc[s][r] * sc[r] + bs[r];
            float res = pre / (1.f + __expf(-pre));
            ushort rb = f2bf(res);
            yb[((size_t)(b * 64 + cb + r)) * NN + h * 64 + p] = rb;
            Yt[p * 76 + cb + r] = rb;
        }
    }
    __syncthreads();

    bf16x8 aY0 = *(const bf16x8*)&Yt[(wv * 16 + l15) * 76 + quad * 8];
    bf16x8 aY1 = *(const bf16x8*)&Yt[(wv * 16 + l15) * 76 + 32 + quad * 8];
    const int nbase = h * 64 + wv * 16 + quad * 4;
    const int vtile = h * 2 + (wv >> 1);
    const int vslot = quad * 8 + (wv & 1) * 4;
    #pragma unroll
    for (int cht = 0; cht < 5; ++cht) {
        bf16x8 bW0 = *(const bf16x8*)&Wq[(cht * 16 + l15) * 76 + quad * 8];
        bf16x8 bW1 = *(const bf16x8*)&Wq[(cht * 16 + l15) * 76 + 32 + quad * 8];
        f32x4 qa = {0.f, 0.f, 0.f, 0.f};
        qa = __builtin_amdgcn_mfma_f32_16x16x32_bf16(aY0, bW0, qa, 0, 0, 0);
        qa = __builtin_amdgcn_mfma_f32_16x16x32_bf16(aY1, bW1, qa, 0, 0, 0);
        const float bias = Bv[cht * 16 + l15];
        const int chn = cht * 16 + l15;
        if (cht == 0) {
            if (l15 < 8) {
                #pragma unroll
                for (int r = 0; r < 4; ++r)
                    q8[((size_t)b * NN + nbase + r) * 8 + chn] = f2bf(qa[r] + bias);
            } else {
                #pragma unroll
                for (int r = 0; r < 4; ++r)
                    ko[((size_t)b * NN + nbase + r) * 8 + (chn - 8)] = f2bf(qa[r] + bias);
            }
        } else {
            const int c = chn - 16;
            ushort u4[4];
            #pragma unroll
            for (int r = 0; r < 4; ++r) u4[r] = f2bf(qa[r] + bias);
            *(uint2*)&vt[(((size_t)(b * 128 + vtile)) * 64 + c) * 32 + vslot] = *(uint2*)u4;
        }
    }
}

// ---------------- flash PAM v10: QT=64, 16 waves (1024 thr), halved V traffic ----------------
// grid 256 (4b x 64nt); wave w owns m-slice [w*256, w*256+256) = 8 blocked-V tiles.
// Zero loop barriers; 4-stage cascade reduce into 4 LDS slots (~74 KB total LDS).
__global__ __launch_bounds__(1024, 4) void flash_pam(
    const ushort* __restrict__ q8,
    const ushort* __restrict__ k8,
    const ushort* __restrict__ vt,
    const ushort* __restrict__ yb,
    const float* __restrict__ x,
    const float* __restrict__ gamma_p,
    float* __restrict__ out)
{
    __shared__ __align__(16) float Osum[4 * 64 * 68];   // [slot][c:64][n:64 stride 68], 69,632 B
    __shared__ float Lw[16][64];
    __shared__ float Ls[64];

    const int tid = threadIdx.x;
    const int bx = blockIdx.x;
    const int b  = bx >> 6;
    const int nt = bx & 63;
    const int n0 = nt * 64;

    const int lane = tid & 63, w = tid >> 6;   // w in 0..15
    const int quad = lane >> 4, l15 = lane & 15;

    const uint4 z4 = {0u, 0u, 0u, 0u};

    // Q B-frags: row n = af*16 + l15, k = d at quad 0; zero pad elsewhere
    bf16x8 bQ[4];
    #pragma unroll
    for (int af = 0; af < 4; ++af) {
        uint4 qv = *(const uint4*)(q8 + ((size_t)b * NN + n0 + af * 16 + l15) * 8);
        uint4 sel = (quad == 0) ? qv : z4;
        bQ[af] = *(bf16x8*)&sel;
    }

    const ushort* kg = k8 + ((size_t)b * NN + w * 256) * 8;
    const ushort* vg = vt + ((size_t)(b * 128 + w * 8)) * 64 * 32;

    f32x4 acc[4][4];
    #pragma unroll
    for (int af = 0; af < 4; ++af)
        #pragma unroll
        for (int ct = 0; ct < 4; ++ct) acc[af][ct] = {0.f, 0.f, 0.f, 0.f};
    float lacc[4] = {0.f, 0.f, 0.f, 0.f};
    const f32x4 zf = {0.f, 0.f, 0.f, 0.f};

    #pragma unroll 2
    for (int t = 0; t < 8; ++t) {
        const int g = t * 32;
        // K A-frags: row m = l15 (+16), k = d at quad 0
        uint4 k0r = *(const uint4*)(kg + (size_t)(g + l15) * 8);
        uint4 k1r = *(const uint4*)(kg + (size_t)(g + 16 + l15) * 8);
        uint4 k0s = (quad == 0) ? k0r : z4;
        uint4 k1s = (quad == 0) ? k1r : z4;
        bf16x8 aK0 = *(bf16x8*)&k0s;
        bf16x8 aK1 = *(bf16x8*)&k1s;

        // V B-frags: blocked layout, lanes-consecutive 64B rows
        bf16x8 vb_[4];
        #pragma unroll
        for (int ct = 0; ct < 4; ++ct)
            vb_[ct] = *(const bf16x8*)(vg + (size_t)t * 2048 + (ct * 16 + l15) * 32 + quad * 8);

        // S^T + exp + pack into PV A-frags, then accumulate
        #pragma unroll
        for (int af = 0; af < 4; ++af) {
            f32x4 s0 = __builtin_amdgcn_mfma_f32_16x16x32_bf16(aK0, bQ[af], zf, 0, 0, 0);
            f32x4 s1 = __builtin_amdgcn_mfma_f32_16x16x32_bf16(aK1, bQ[af], zf, 0, 0, 0);
            union { ushort u[8]; bf16x8 v; } pk;
            #pragma unroll
            for (int r = 0; r < 4; ++r) {
                float e = __expf(s0[r]);
                lacc[af] += e;
                pk.u[r] = f2bf(e);
            }
            #pragma unroll
            for (int r = 0; r < 4; ++r) {
                float e = __expf(s1[r]);
                lacc[af] += e;
                pk.u[4 + r] = f2bf(e);
            }
            #pragma unroll
            for (int ct = 0; ct < 4; ++ct)
                acc[af][ct] = __builtin_amdgcn_mfma_f32_16x16x32_bf16(pk.v, vb_[ct], acc[af][ct], 0, 0, 0);
        }
    }

    // per-wave l: reduce across quads (lanes sharing l15)
    #pragma unroll
    for (int af = 0; af < 4; ++af) {
        lacc[af] += __shfl_xor(lacc[af], 16, 64);
        lacc[af] += __shfl_xor(lacc[af], 32, 64);
    }
    if (quad == 0) {
        #pragma unroll
        for (int af = 0; af < 4; ++af) Lw[w][af * 16 + l15] = lacc[af];
    }

    // 4-stage cascade reduce into 4 slots
    if (w >= 12) {
        #pragma unroll
        for (int af = 0; af < 4; ++af)
            #pragma unroll
            for (int ct = 0; ct < 4; ++ct)
                *(f32x4*)&Osum[((w - 12) * 64 + ct * 16 + l15) * 68 + af * 16 + quad * 4] = acc[af][ct];
    }
    __syncthreads();
    if (w >= 8 && w < 12) {
        #pragma unroll
        for (int af = 0; af < 4; ++af)
            #pragma unroll
            for (int ct = 0; ct < 4; ++ct) {
                float* p = &Osum[((w - 8) * 64 + ct * 16 + l15) * 68 + af * 16 + quad * 4];
                f32x4 v = *(const f32x4*)p;
                *(f32x4*)p = v + acc[af][ct];
            }
    }
    __syncthreads();
    if (w >= 4 && w < 8) {
        #pragma unroll
        for (int af = 0; af < 4; ++af)
            #pragma unroll
            for (int ct = 0; ct < 4; ++ct) {
                float* p = &Osum[((w - 4) * 64 + ct * 16 + l15) * 68 + af * 16 + quad * 4];
                f32x4 v = *(const f32x4*)p;
                *(f32x4*)p = v + acc[af][ct];
            }
    }
    __syncthreads();
    if (w < 4) {
        #pragma unroll
        for (int af = 0; af < 4; ++af)
            #pragma unroll
            for (int ct = 0; ct < 4; ++ct) {
                float* p = &Osum[(w * 64 + ct * 16 + l15) * 68 + af * 16 + quad * 4];
                f32x4 v = *(const f32x4*)p;
                *(f32x4*)p = v + acc[af][ct];
            }
    }
    if (tid < 64) {
        float s = 0.f;
        #pragma unroll
        for (int wv = 0; wv < 16; ++wv) s += Lw[wv][tid];
        Ls[tid] = s;
    }
    __syncthreads();

    // epilogue: thread -> (c = tid>>4, n = (tid&15)*4 .. +3); sum 4 slots
    {
        const int c = tid >> 4, nn = (tid & 15) * 4;
        f32x4 o = {0.f, 0.f, 0.f, 0.f};
        #pragma unroll
        for (int s = 0; s < 4; ++s)
            o += *(const f32x4*)&Osum[(s * 64 + c) * 68 + nn];
        const float g2 = 2.f * gamma_p[0];
        const size_t idx = ((size_t)b * 64 + c) * NN + n0 + nn;
        f32x4 xv = *(const f32x4*)(x + idx);
        uint2 yv2 = *(const uint2*)(yb + idx);
        float yf[4] = { bflo(yv2.x), bfhi(yv2.x), bflo(yv2.y), bfhi(yv2.y) };
        f32x4 res;
        #pragma unroll
        for (int u = 0; u < 4; ++u)
            res[u] = xv[u] + 2.f * yf[u] + g2 * o[u] / Ls[nn + u];
        *(f32x4*)(out + idx) = res;
    }
}

extern "C" void kernel_launch(void* const* d_in, const int* in_sizes, int n_in,
                              void* d_out, int out_size, void* d_ws, size_t ws_size,
                              hipStream_t stream) {
    const float* x    = (const float*)d_in[0];
    const float* w1   = (const float*)d_in[1];
    const float* g1   = (const float*)d_in[2];
    const float* b1   = (const float*)d_in[3];
    const float* m1   = (const float*)d_in[4];
    const float* v1   = (const float*)d_in[5];
    const float* w2   = (const float*)d_in[6];
    const float* g2   = (const float*)d_in[7];
    const float* b2   = (const float*)d_in[8];
    const float* m2   = (const float*)d_in[9];
    const float* v2   = (const float*)d_in[10];
    const float* qw   = (const float*)d_in[11];
    const float* qb   = (const float*)d_in[12];
    const float* kw   = (const float*)d_in[13];
    const float* kb   = (const float*)d_in[14];
    const float* vw   = (const float*)d_in[15];
    const float* vb   = (const float*)d_in[16];
    const float* gam  = (const float*)d_in[17];
    float* outp = (float*)d_out;

    float* ws = (float*)d_ws;
    ushort* xt  = (ushort*)ws;                 // 1,048,576 ush
    ushort* yb  = (ushort*)(ws + 524288);      // 1,048,576 ush bf16 (y)
    ushort* q8  = (ushort*)(ws + 1572864);     // 131,072 ush bf16
    ushort* kk  = (ushort*)(ws + 1703936);     // 131,072 ush bf16
    ushort* vv  = (ushort*)(ws + 1769472);     // 1,048,576 ush bf16 (blocked layout)
    float*  S   = ws + 2326528;                // scratch
    ushort* y1t = (ushort*)S;                  // 524,288 ush
    ushort* W1r = (ushort*)(S + 262144);       // 18,432 ush
    ushort* W2r = (ushort*)(S + 271360);       // 18,432 ush

    prep<<<260, 256, 0, stream>>>(x, w1, w2, xt, W1r, W2r);
    conv1_mfma<<<dim3(64, NB), 256, 0, stream>>>(xt, W1r, g1, b1, m1, v1, y1t);
    conv2qkv<<<dim3(64, NB), 256, 0, stream>>>(y1t, W2r, g2, b2, m2, v2,
                                               qw, qb, kw, kb, vw, vb,
                                               yb, q8, kk, vv);
    flash_pam<<<256, 1024, 0, stream>>>(q8, kk, vv, yb, x, gam, outp);
}

// Round 13
// 130.627 us; speedup vs baseline: 1.0850x; 1.0850x over previous
//
#include <hip/hip_runtime.h>
#include <hip/hip_bf16.h>

#define NB 4
#define NN 4096

typedef short  bf16x8 __attribute__((ext_vector_type(8)));
typedef float  f32x4  __attribute__((ext_vector_type(4)));

static __device__ __forceinline__ ushort f2bf(float f) {
    unsigned u = __float_as_uint(f);
    u += 0x7fffu + ((u >> 16) & 1u);
    return (ushort)(u >> 16);
}

// ---------------- prep: x -> xt (channel-last bf16), conv weights reordered bf16 ----------------
__global__ __launch_bounds__(256) void prep(
    const float* __restrict__ x, const float* __restrict__ w1, const float* __restrict__ w2,
    ushort* __restrict__ xt, ushort* __restrict__ W1r, ushort* __restrict__ W2r)
{
    const int tid = threadIdx.x;
    const int blk = blockIdx.x;
    if (blk < 256) {
        __shared__ float Ts[64][66];
        const int b = blk >> 6, n0 = (blk & 63) * 64;
        const int wv = tid >> 6, lane = tid & 63;
        #pragma unroll
        for (int i = 0; i < 16; ++i) {
            int ci = i * 4 + wv, nn = lane;
            Ts[ci][nn] = x[((size_t)b * 64 + ci) * NN + n0 + nn];
        }
        __syncthreads();
        #pragma unroll
        for (int i = 0; i < 16; ++i) {
            int nn = i * 4 + wv, ci = lane;
            xt[((size_t)b * NN + n0 + nn) * 64 + ci] = f2bf(Ts[ci][nn]);
        }
    } else if (blk < 258) {
        const int base = (blk - 256) * 9216;
        #pragma unroll
        for (int i = 0; i < 36; ++i) {
            int e = base + i * 256 + tid;
            int co = e / 576, k = e % 576, tap = k >> 6, ci = k & 63;
            W1r[e] = f2bf(w1[((size_t)co * 64 + ci) * 9 + tap]);
        }
    } else {
        const int base = (blk - 258) * 9216;
        #pragma unroll
        for (int i = 0; i < 36; ++i) {
            int e = base + i * 256 + tid;
            int co = e / 288, k = e % 288, tap = k >> 5, ci = k & 31;
            W2r[e] = f2bf(w2[((size_t)co * 32 + ci) * 9 + tap]);
        }
    }
}

// ---------------- conv1: 64ci -> 32co, MFMA implicit GEMM ----------------
__global__ __launch_bounds__(256) void conv1_mfma(
    const ushort* __restrict__ xt, const ushort* __restrict__ W1r,
    const float* __restrict__ bng, const float* __restrict__ bnb,
    const float* __restrict__ bnm, const float* __restrict__ bnv,
    ushort* __restrict__ y1t)
{
    __shared__ __align__(16) ushort As[32 * 600];
    __shared__ __align__(16) ushort Xs[24 * 66 * 8];

    const int tid = threadIdx.x;
    const int h = blockIdx.x, b = blockIdx.y;

    #pragma unroll
    for (int i = 0; i < 9; ++i) {
        int cid = i * 256 + tid;
        int row = cid / 72, off = cid % 72;
        *(uint4*)&As[row * 600 + off * 8] = *(const uint4*)(W1r + (size_t)cid * 8);
    }
    #pragma unroll
    for (int r = 0; r < 3; ++r) {
        int gh = h - 1 + r;
        #pragma unroll
        for (int i = 0; i < 2; ++i) {
            int cid = i * 256 + tid;
            int w_ = cid >> 3, cc = cid & 7;
            uint4 v = {0, 0, 0, 0};
            if ((unsigned)gh < 64u)
                v = *(const uint4*)(xt + ((size_t)(b * NN + gh * 64) * 64) + (size_t)cid * 8);
            *(uint4*)&Xs[((r * 8 + cc) * 66 + (w_ + 1)) * 8] = v;
        }
    }
    if (tid < 48) {
        int r = tid >> 4, q = tid & 15, cc = q >> 1, side = (q & 1) * 65;
        uint4 z = {0, 0, 0, 0};
        *(uint4*)&Xs[((r * 8 + cc) * 66 + side) * 8] = z;
    }
    __syncthreads();

    const int lane = tid & 63, wv = tid >> 6;
    const int quad = lane >> 4, l15 = lane & 15;
    const int ch = wv & 1, ph = wv >> 1;

    f32x4 acc[2] = {{0.f,0.f,0.f,0.f},{0.f,0.f,0.f,0.f}};
    #pragma unroll
    for (int kk = 0; kk < 18; ++kk) {
        const int tap = kk >> 1;
        const int dyr = tap / 3, dx = tap % 3;
        bf16x8 af = *(const bf16x8*)&As[(ch * 16 + l15) * 600 + kk * 32 + quad * 8];
        #pragma unroll
        for (int s = 0; s < 2; ++s) {
            int p = ph * 32 + s * 16 + l15;
            bf16x8 bf = *(const bf16x8*)&Xs[((dyr * 8 + (kk & 1) * 4 + quad) * 66 + p + dx) * 8];
            acc[s] = __builtin_amdgcn_mfma_f32_16x16x32_bf16(af, bf, acc[s], 0, 0, 0);
        }
    }

    const int cb = ch * 16 + quad * 4;
    float sc[4], bs[4];
    #pragma unroll
    for (int r = 0; r < 4; ++r) {
        int co = cb + r;
        sc[r] = bng[co] / sqrtf(bnv[co] + 1e-5f);
        bs[r] = bnb[co] - bnm[co] * sc[r];
    }
    #pragma unroll
    for (int s = 0; s < 2; ++s) {
        int p = ph * 32 + s * 16 + l15;
        ushort u4[4];
        #pragma unroll
        for (int r = 0; r < 4; ++r) {
            float pre = acc[s][r] * sc[r] + bs[r];
            u4[r] = f2bf(pre / (1.f + __expf(-pre)));
        }
        *(uint2*)&y1t[((size_t)(b * NN + h * 64 + p)) * 32 + cb] = *(uint2*)u4;
    }
}

// ---------------- conv2 + fused qkv ----------------
// vt in BLOCKED layout: vt[b][tile(128)][c(64)][slot(32)], slot = quad*8 + half*4 + r
// holding pixel m = tile*32 + half*16 + quad*4 + r  (matches flash PV fragment order).
__global__ __launch_bounds__(256) void conv2qkv(
    const ushort* __restrict__ y1t, const ushort* __restrict__ W2r,
    const float* __restrict__ bng, const float* __restrict__ bnb,
    const float* __restrict__ bnm, const float* __restrict__ bnv,
    const float* __restrict__ qw, const float* __restrict__ qb,
    const float* __restrict__ kw, const float* __restrict__ kb,
    const float* __restrict__ vw, const float* __restrict__ vb,
    float* __restrict__ y, ushort* __restrict__ q8,
    ushort* __restrict__ ko, ushort* __restrict__ vt)
{
    __shared__ __align__(16) ushort As[64 * 312];
    __shared__ __align__(16) ushort Xs[12 * 66 * 8];
    __shared__ __align__(16) ushort Yt[64 * 76];
    __shared__ __align__(16) ushort Wq[80 * 76];
    __shared__ float Bv[80];

    const int tid = threadIdx.x;
    const int h = blockIdx.x, b = blockIdx.y;

    #pragma unroll
    for (int i = 0; i < 9; ++i) {
        int cid = i * 256 + tid;
        int row = cid / 36, off = cid % 36;
        *(uint4*)&As[row * 312 + off * 8] = *(const uint4*)(W2r + (size_t)cid * 8);
    }
    #pragma unroll
    for (int r = 0; r < 3; ++r) {
        int gh = h - 1 + r;
        int cid = tid;
        int w_ = cid >> 2, cc = cid & 3;
        uint4 v = {0, 0, 0, 0};
        if ((unsigned)gh < 64u)
            v = *(const uint4*)(y1t + ((size_t)(b * NN + gh * 64) * 32) + (size_t)cid * 8);
        *(uint4*)&Xs[((r * 4 + cc) * 66 + (w_ + 1)) * 8] = v;
    }
    if (tid < 24) {
        int r = tid >> 3, q = tid & 7, cc = q >> 1, side = (q & 1) * 65;
        uint4 z = {0, 0, 0, 0};
        *(uint4*)&Xs[((r * 4 + cc) * 66 + side) * 8] = z;
    }
    for (int i = tid; i < 2560; i += 256) {
        int chw = i >> 5, c2 = (i & 31) * 2;
        const float* src = (chw < 8) ? (qw + chw * 64 + c2)
                         : (chw < 16) ? (kw + (chw - 8) * 64 + c2)
                         : (vw + (chw - 16) * 64 + c2);
        float2 v2 = *(const float2*)src;
        *(unsigned*)&Wq[chw * 76 + c2] = ((unsigned)f2bf(v2.y) << 16) | f2bf(v2.x);
    }
    if (tid < 80) Bv[tid] = (tid < 8) ? qb[tid] : (tid < 16) ? kb[tid - 8] : vb[tid - 16];
    __syncthreads();

    const int lane = tid & 63, wv = tid >> 6;
    const int quad = lane >> 4, l15 = lane & 15;

    f32x4 acc[4] = {{0.f,0.f,0.f,0.f},{0.f,0.f,0.f,0.f},{0.f,0.f,0.f,0.f},{0.f,0.f,0.f,0.f}};
    #pragma unroll
    for (int kk = 0; kk < 9; ++kk) {
        const int dyr = kk / 3, dx = kk % 3;
        bf16x8 af = *(const bf16x8*)&As[(wv * 16 + l15) * 312 + kk * 32 + quad * 8];
        #pragma unroll
        for (int s = 0; s < 4; ++s) {
            int p = s * 16 + l15;
            bf16x8 bf = *(const bf16x8*)&Xs[((dyr * 4 + quad) * 66 + p + dx) * 8];
            acc[s] = __builtin_amdgcn_mfma_f32_16x16x32_bf16(af, bf, acc[s], 0, 0, 0);
        }
    }

    const int cb = wv * 16 + quad * 4;
    float sc[4], bs[4];
    #pragma unroll
    for (int r = 0; r < 4; ++r) {
        int co = cb + r;
        sc[r] = bng[co] / sqrtf(bnv[co] + 1e-5f);
        bs[r] = bnb[co] - bnm[co] * sc[r];
    }
    #pragma unroll
    for (int s = 0; s < 4; ++s) {
        int p = s * 16 + l15;
        #pragma unroll
        for (int r = 0; r < 4; ++r) {
            float pre = acc[s][r] * sc[r] + bs[r];
            float res = pre / (1.f + __expf(-pre));
            y[((size_t)(b * 64 + cb + r)) * NN + h * 64 + p] = res;
            Yt[p * 76 + cb + r] = f2bf(res);
        }
    }
    __syncthreads();

    bf16x8 aY0 = *(const bf16x8*)&Yt[(wv * 16 + l15) * 76 + quad * 8];
    bf16x8 aY1 = *(const bf16x8*)&Yt[(wv * 16 + l15) * 76 + 32 + quad * 8];
    const int nbase = h * 64 + wv * 16 + quad * 4;
    // blocked-vt indices: tile = h*2 + (wv>>1); slot = quad*8 + (wv&1)*4
    const int vtile = h * 2 + (wv >> 1);
    const int vslot = quad * 8 + (wv & 1) * 4;
    #pragma unroll
    for (int cht = 0; cht < 5; ++cht) {
        bf16x8 bW0 = *(const bf16x8*)&Wq[(cht * 16 + l15) * 76 + quad * 8];
        bf16x8 bW1 = *(const bf16x8*)&Wq[(cht * 16 + l15) * 76 + 32 + quad * 8];
        f32x4 qa = {0.f, 0.f, 0.f, 0.f};
        qa = __builtin_amdgcn_mfma_f32_16x16x32_bf16(aY0, bW0, qa, 0, 0, 0);
        qa = __builtin_amdgcn_mfma_f32_16x16x32_bf16(aY1, bW1, qa, 0, 0, 0);
        const float bias = Bv[cht * 16 + l15];
        const int chn = cht * 16 + l15;
        if (cht == 0) {
            if (l15 < 8) {
                #pragma unroll
                for (int r = 0; r < 4; ++r)
                    q8[((size_t)b * NN + nbase + r) * 8 + chn] = f2bf(qa[r] + bias);
            } else {
                #pragma unroll
                for (int r = 0; r < 4; ++r)
                    ko[((size_t)b * NN + nbase + r) * 8 + (chn - 8)] = f2bf(qa[r] + bias);
            }
        } else {
            const int c = chn - 16;
            ushort u4[4];
            #pragma unroll
            for (int r = 0; r < 4; ++r) u4[r] = f2bf(qa[r] + bias);
            *(uint2*)&vt[(((size_t)(b * 128 + vtile)) * 64 + c) * 32 + vslot] = *(uint2*)u4;
        }
    }
}

// ---------------- flash PAM v8: blocked-V coalesced loads, two-stage LDS reduce ----------------
// grid 512 (4b x 128nt), 512 threads; zero loop barriers.
__global__ __launch_bounds__(512, 4) void flash_pam(
    const ushort* __restrict__ q8,
    const ushort* __restrict__ k8,
    const ushort* __restrict__ vt,
    const float* __restrict__ y,
    const float* __restrict__ x,
    const float* __restrict__ gamma_p,
    float* __restrict__ out)
{
    __shared__ __align__(16) float Osum[4 * 2304];   // [slot][c:64 stride 36][n:32], 36,864 B
    __shared__ float Lw[8][32];
    __shared__ float Ls[32];

    const int tid = threadIdx.x;
    const int bx = blockIdx.x;
    const int b  = bx >> 7;
    const int nt = bx & 127;
    const int n0 = nt * 32;

    const int lane = tid & 63, w = tid >> 6;   // w in 0..7
    const int quad = lane >> 4, l15 = lane & 15;

    const uint4 z4 = {0u, 0u, 0u, 0u};

    // Q B-frags: row n = l15 (+16), k = d at quad 0; zero pad elsewhere
    bf16x8 bQ[2];
    #pragma unroll
    for (int af = 0; af < 2; ++af) {
        uint4 qv = *(const uint4*)(q8 + ((size_t)b * NN + n0 + af * 16 + l15) * 8);
        uint4 sel = (quad == 0) ? qv : z4;
        bQ[af] = *(bf16x8*)&sel;
    }

    const ushort* kg = k8 + ((size_t)b * NN + w * 512) * 8;
    // blocked V: wave w owns tiles w*16 .. w*16+15 of batch b
    const ushort* vg = vt + ((size_t)(b * 128 + w * 16)) * 64 * 32;

    f32x4 acc[2][4] = {{{0.f,0.f,0.f,0.f},{0.f,0.f,0.f,0.f},{0.f,0.f,0.f,0.f},{0.f,0.f,0.f,0.f}},
                       {{0.f,0.f,0.f,0.f},{0.f,0.f,0.f,0.f},{0.f,0.f,0.f,0.f},{0.f,0.f,0.f,0.f}}};
    float lacc[2] = {0.f, 0.f};
    const f32x4 zf = {0.f, 0.f, 0.f, 0.f};

    #pragma unroll 2
    for (int t = 0; t < 16; ++t) {
        const int g = t * 32;
        // K A-frags: row m = l15 (+16), k = d at quad 0
        uint4 k0r = *(const uint4*)(kg + (size_t)(g + l15) * 8);
        uint4 k1r = *(const uint4*)(kg + (size_t)(g + 16 + l15) * 8);
        uint4 k0s = (quad == 0) ? k0r : z4;
        uint4 k1s = (quad == 0) ? k1r : z4;
        bf16x8 aK0 = *(bf16x8*)&k0s;
        bf16x8 aK1 = *(bf16x8*)&k1s;

        // V B-frags: blocked layout -> lanes read consecutive 64B rows (1KB burst)
        bf16x8 vb_[4];
        #pragma unroll
        for (int ct = 0; ct < 4; ++ct)
            vb_[ct] = *(const bf16x8*)(vg + (size_t)t * 2048 + (ct * 16 + l15) * 32 + quad * 8);

        // S^T: D[m=quad*4+r(+16)][n=l15(+16af)]
        f32x4 s0[2], s1[2];
        #pragma unroll
        for (int af = 0; af < 2; ++af) {
            s0[af] = __builtin_amdgcn_mfma_f32_16x16x32_bf16(aK0, bQ[af], zf, 0, 0, 0);
            s1[af] = __builtin_amdgcn_mfma_f32_16x16x32_bf16(aK1, bQ[af], zf, 0, 0, 0);
        }

        // exp + pack directly into PV A-frags (k-slot matches vt slot order)
        bf16x8 pa[2];
        #pragma unroll
        for (int af = 0; af < 2; ++af) {
            union { ushort u[8]; bf16x8 v; } pk;
            #pragma unroll
            for (int r = 0; r < 4; ++r) {
                float e = __expf(s0[af][r]);
                lacc[af] += e;
                pk.u[r] = f2bf(e);
            }
            #pragma unroll
            for (int r = 0; r < 4; ++r) {
                float e = __expf(s1[af][r]);
                lacc[af] += e;
                pk.u[4 + r] = f2bf(e);
            }
            pa[af] = pk.v;
        }

        // O += P V (no LDS, no barrier)
        #pragma unroll
        for (int af = 0; af < 2; ++af)
            #pragma unroll
            for (int ct = 0; ct < 4; ++ct)
                acc[af][ct] = __builtin_amdgcn_mfma_f32_16x16x32_bf16(pa[af], vb_[ct], acc[af][ct], 0, 0, 0);
    }

    // per-wave l: reduce across quads (lanes sharing l15)
    #pragma unroll
    for (int af = 0; af < 2; ++af) {
        lacc[af] += __shfl_xor(lacc[af], 16, 64);
        lacc[af] += __shfl_xor(lacc[af], 32, 64);
    }
    if (quad == 0) {
        Lw[w][l15]      = lacc[0];
        Lw[w][16 + l15] = lacc[1];
    }

    // two-stage O reduce: waves 4-7 write slots 0-3; barrier; waves 0-3 accumulate
    if (w >= 4) {
        #pragma unroll
        for (int af = 0; af < 2; ++af)
            #pragma unroll
            for (int ct = 0; ct < 4; ++ct)
                *(f32x4*)&Osum[(w - 4) * 2304 + (ct * 16 + l15) * 36 + af * 16 + quad * 4] = acc[af][ct];
    }
    __syncthreads();
    if (w < 4) {
        #pragma unroll
        for (int af = 0; af < 2; ++af)
            #pragma unroll
            for (int ct = 0; ct < 4; ++ct) {
                float* p = &Osum[w * 2304 + (ct * 16 + l15) * 36 + af * 16 + quad * 4];
                f32x4 v = *(const f32x4*)p;
                *(f32x4*)p = v + acc[af][ct];
            }
    }
    if (tid < 32) Ls[tid] = Lw[0][tid] + Lw[1][tid] + Lw[2][tid] + Lw[3][tid]
                          + Lw[4][tid] + Lw[5][tid] + Lw[6][tid] + Lw[7][tid];
    __syncthreads();

    // epilogue: thread -> (c = tid>>3, n = (tid&7)*4 .. +3); sum 4 slots
    {
        const int c = tid >> 3, nn = (tid & 7) * 4;
        f32x4 o = {0.f, 0.f, 0.f, 0.f};
        #pragma unroll
        for (int s = 0; s < 4; ++s)
            o += *(const f32x4*)&Osum[s * 2304 + c * 36 + nn];
        const float g2 = 2.f * gamma_p[0];
        const size_t idx = ((size_t)b * 64 + c) * NN + n0 + nn;
        f32x4 xv = *(const f32x4*)(x + idx);
        f32x4 yv = *(const f32x4*)(y + idx);
        f32x4 res;
        #pragma unroll
        for (int u = 0; u < 4; ++u)
            res[u] = xv[u] + 2.f * yv[u] + g2 * o[u] / Ls[nn + u];
        *(f32x4*)(out + idx) = res;
    }
}

extern "C" void kernel_launch(void* const* d_in, const int* in_sizes, int n_in,
                              void* d_out, int out_size, void* d_ws, size_t ws_size,
                              hipStream_t stream) {
    const float* x    = (const float*)d_in[0];
    const float* w1   = (const float*)d_in[1];
    const float* g1   = (const float*)d_in[2];
    const float* b1   = (const float*)d_in[3];
    const float* m1   = (const float*)d_in[4];
    const float* v1   = (const float*)d_in[5];
    const float* w2   = (const float*)d_in[6];
    const float* g2   = (const float*)d_in[7];
    const float* b2   = (const float*)d_in[8];
    const float* m2   = (const float*)d_in[9];
    const float* v2   = (const float*)d_in[10];
    const float* qw   = (const float*)d_in[11];
    const float* qb   = (const float*)d_in[12];
    const float* kw   = (const float*)d_in[13];
    const float* kb   = (const float*)d_in[14];
    const float* vw   = (const float*)d_in[15];
    const float* vb   = (const float*)d_in[16];
    const float* gam  = (const float*)d_in[17];
    float* outp = (float*)d_out;

    float* ws = (float*)d_ws;
    ushort* xt  = (ushort*)ws;                 // 1,048,576 ush
    float*  y   = ws + 524288;                 // 1,048,576 f
    ushort* q8  = (ushort*)(ws + 1572864);     // 131,072 ush bf16
    ushort* kk  = (ushort*)(ws + 1703936);     // 131,072 ush bf16
    ushort* vv  = (ushort*)(ws + 1769472);     // 1,048,576 ush bf16 (blocked layout)
    float*  S   = ws + 2326528;                // scratch
    ushort* y1t = (ushort*)S;                  // 524,288 ush
    ushort* W1r = (ushort*)(S + 262144);       // 18,432 ush
    ushort* W2r = (ushort*)(S + 271360);       // 18,432 ush

    prep<<<260, 256, 0, stream>>>(x, w1, w2, xt, W1r, W2r);
    conv1_mfma<<<dim3(64, NB), 256, 0, stream>>>(xt, W1r, g1, b1, m1, v1, y1t);
    conv2qkv<<<dim3(64, NB), 256, 0, stream>>>(y1t, W2r, g2, b2, m2, v2,
                                               qw, qb, kw, kb, vw, vb,
                                               y, q8, kk, vv);
    flash_pam<<<512, 512, 0, stream>>>(q8, kk, vv, y, x, gam, outp);
}